// Round 2
// baseline (10672.453 us; speedup 1.0000x reference)
//
#include <hip/hip_runtime.h>
#include <hip/hip_bf16.h>

// DIEN: seq_len -> sort -> qp(prelu) -> GRU1 -> attention MLP + softmax -> GRU2(att) -> concat out
// Shapes: B=2048, T=200, D=128, H=128.
// ws layout: sl[B] i32 | perm[B] i32 | qp[B*128] f32 | alphas[B*T] f32 | rnn1[B*T*128] bf16 (~108MB)

#define BB 2048
#define TT_ 200
#define DD 128
#define HH 128

__device__ __forceinline__ float sigmoidf_(float x) { return 1.0f / (1.0f + __expf(-x)); }

// ---------------- seq_len: first t with mask==0, else T ----------------
__global__ __launch_bounds__(256) void k_seqlen(const int* __restrict__ mask, int* __restrict__ sl) {
    int b = blockIdx.x * 256 + threadIdx.x;
    if (b >= BB) return;
    const int* mrow = mask + (size_t)b * TT_;
    int s = TT_;
    for (int t = 0; t < TT_; ++t) {
        if (mrow[t] == 0) { s = t; break; }
    }
    sl[b] = s;
}

// ---------------- counting sort by seq_len (load balance for GRU blocks) ----------------
__global__ __launch_bounds__(256) void k_sort(const int* __restrict__ sl, int* __restrict__ perm) {
    __shared__ int offs[TT_ + 1];
    int tid = threadIdx.x;
    for (int i = tid; i <= TT_; i += 256) offs[i] = 0;
    __syncthreads();
    for (int b = tid; b < BB; b += 256) atomicAdd(&offs[sl[b]], 1);
    __syncthreads();
    if (tid == 0) {
        int acc = 0;
        for (int v = 0; v <= TT_; ++v) { int c = offs[v]; offs[v] = acc; acc += c; }
    }
    __syncthreads();
    for (int b = tid; b < BB; b += 256) {
        int p = atomicAdd(&offs[sl[b]], 1);
        perm[p] = b;
    }
}

// ---------------- qp = prelu(q @ wq + bq) ----------------
__global__ __launch_bounds__(128) void k_qp(const float* __restrict__ item_eb, const float* __restrict__ wq,
                                            const float* __restrict__ bq, const float* __restrict__ alpha,
                                            float* __restrict__ qp) {
    int b = blockIdx.x, j = threadIdx.x;
    __shared__ float qs[DD];
    qs[j] = item_eb[(size_t)b * DD + j];
    __syncthreads();
    float acc = bq[j];
#pragma unroll 4
    for (int k = 0; k < DD; ++k) acc += qs[k] * wq[k * HH + j];
    float v = acc > 0.f ? acc : alpha[j] * acc;
    qp[(size_t)b * HH + j] = v;
}

// ---------------- GRU (shared for GRU1 / GRU2-with-attention) ----------------
// 256 threads, R=8 batch rows per block. z-phase: 256 outputs (thread j -> col j).
// c-phase: 128 outputs, split-K across thread halves. Early exit at per-block max seq_len.
template <bool IS_GRU2>
__global__ __launch_bounds__(256) void k_gru(const float* __restrict__ x_f32,
                                             const __hip_bfloat16* __restrict__ x_bf,
                                             const float* __restrict__ gk, const float* __restrict__ gb,
                                             const float* __restrict__ ck, const float* __restrict__ cb,
                                             const float* __restrict__ alphas,
                                             const int* __restrict__ perm, const int* __restrict__ slv,
                                             __hip_bfloat16* __restrict__ rnn1_out,
                                             float* __restrict__ out) {
    constexpr int R = 8;
    __shared__ __align__(16) float xc[R][2 * HH];  // [x | h], then [x | r*h]
    __shared__ float hb[R][HH];
    __shared__ float ub[R][HH];
    __shared__ float cp[R][HH];
    __shared__ float av[R];
    __shared__ int rid_s[R], sl_s[R];
    int tid = threadIdx.x;
    if (tid < R) {
        int rr = perm[blockIdx.x * R + tid];
        rid_s[tid] = rr;
        sl_s[tid] = slv[rr];
    }
    for (int i = tid; i < R * HH; i += 256) ((float*)hb)[i] = 0.f;
    __syncthreads();
    int rid[R], slr[R], tmax = 0;
#pragma unroll
    for (int r = 0; r < R; ++r) {
        rid[r] = rid_s[r];
        slr[r] = sl_s[r];
        tmax = max(tmax, slr[r]);
    }

    for (int t = 0; t < tmax; ++t) {
        // stage x_t and h
#pragma unroll
        for (int i = 0; i < 4; ++i) {
            int lin = i * 256 + tid;
            int r = lin >> 7, c = lin & 127;
            int row = rid_s[r];
            float xv;
            if constexpr (IS_GRU2)
                xv = __bfloat162float(x_bf[((size_t)row * TT_ + t) * HH + c]);
            else
                xv = x_f32[((size_t)row * TT_ + t) * HH + c];
            xc[r][c] = xv;
            xc[r][HH + c] = hb[r][c];
        }
        if constexpr (IS_GRU2) {
            if (tid < R) av[tid] = alphas[(size_t)rid_s[tid] * TT_ + t];
        }
        __syncthreads();

        // z-phase: z[j] = sigmoid(sum_k xc[k] * gk[k][j] + gb[j]); j=tid over 256 cols
        float acc[R];
        float bj = gb[tid];
#pragma unroll
        for (int r = 0; r < R; ++r) acc[r] = bj;
#pragma unroll 2
        for (int k0 = 0; k0 < 2 * HH; k0 += 4) {
            float4 xv[R];
#pragma unroll
            for (int r = 0; r < R; ++r) xv[r] = *(const float4*)&xc[r][k0];
#pragma unroll
            for (int kk = 0; kk < 4; ++kk) {
                float w = gk[(k0 + kk) * (2 * HH) + tid];
#pragma unroll
                for (int r = 0; r < R; ++r) acc[r] += ((const float*)&xv[r])[kk] * w;
            }
        }
        float zg[R];
#pragma unroll
        for (int r = 0; r < R; ++r) zg[r] = sigmoidf_(acc[r]);
        if (tid >= HH) {
#pragma unroll
            for (int r = 0; r < R; ++r) ub[r][tid - HH] = zg[r];
        }
        __syncthreads();
        if (tid < HH) {
#pragma unroll
            for (int r = 0; r < R; ++r) xc[r][HH + tid] = zg[r] * hb[r][tid];
        }
        __syncthreads();

        // c-phase: c[j] = tanh(sum_k [x|r*h][k] * ck[k][j] + cb[j]); split-K across halves
        int jj = tid & (HH - 1);
        int kb = (tid >> 7) * HH;
        float a2[R];
#pragma unroll
        for (int r = 0; r < R; ++r) a2[r] = 0.f;
#pragma unroll 2
        for (int k0 = 0; k0 < HH; k0 += 4) {
            float4 xv[R];
#pragma unroll
            for (int r = 0; r < R; ++r) xv[r] = *(const float4*)&xc[r][kb + k0];
#pragma unroll
            for (int kk = 0; kk < 4; ++kk) {
                float w = ck[(kb + k0 + kk) * HH + jj];
#pragma unroll
                for (int r = 0; r < R; ++r) a2[r] += ((const float*)&xv[r])[kk] * w;
            }
        }
        if (tid >= HH) {
#pragma unroll
            for (int r = 0; r < R; ++r) cp[r][jj] = a2[r];
        }
        __syncthreads();
        if (tid < HH) {
#pragma unroll
            for (int r = 0; r < R; ++r) {
                float c = tanhf(a2[r] + cp[r][jj] + cb[jj]);
                float u = ub[r][jj];
                if constexpr (IS_GRU2) u *= (1.f - av[r]);
                float h = hb[r][jj];
                float nh = u * h + (1.f - u) * c;
                if (t < slr[r]) {
                    hb[r][jj] = nh;
                    if constexpr (!IS_GRU2)
                        rnn1_out[((size_t)rid[r] * TT_ + t) * HH + jj] = __float2bfloat16(nh);
                }
            }
        }
        __syncthreads();
    }

    if constexpr (IS_GRU2) {
        if (tid < HH) {
#pragma unroll
            for (int r = 0; r < R; ++r) out[(size_t)rid[r] * (4 * HH) + 3 * HH + tid] = hb[r][tid];
        }
    }
}

// ---------------- attention MLP + masked softmax ----------------
// din@w1 folded: W_eff[k][o] = w1b - w1c + qp[k]*w1d  (per-b, LDS); qc[o] = b1 + qp@(w1a+w1c)
#define TCH 12
__global__ __launch_bounds__(256) void k_mlp(const __hip_bfloat16* __restrict__ rnn1, const float* __restrict__ qp,
                                             const float* __restrict__ w1, const float* __restrict__ b1,
                                             const float* __restrict__ w2, const float* __restrict__ b2,
                                             const float* __restrict__ w3, const float* __restrict__ b3,
                                             const int* __restrict__ slv, float* __restrict__ alphas) {
    __shared__ float Weff[DD][80];
    __shared__ float qc[80];
    __shared__ float w2s[80 * 40];
    __shared__ float w3s[40], b2s[40];
    __shared__ float qps[DD];
    __shared__ float xs[TCH][DD];
    __shared__ float a1s[TCH][80];
    __shared__ float a2s[TCH][40];
    __shared__ float scores[TT_];
    __shared__ float red[8];
    int b = blockIdx.x, tid = threadIdx.x;
    int sl = slv[b];
    if (tid < DD) qps[tid] = qp[(size_t)b * DD + tid];
    if (tid < 40) { w3s[tid] = w3[tid]; b2s[tid] = b2[tid]; }
    __syncthreads();
    for (int idx = tid; idx < DD * 80; idx += 256) {
        int k = idx / 80, o = idx - 80 * k;
        Weff[k][o] = w1[(128 + k) * 80 + o] - w1[(256 + k) * 80 + o] + qps[k] * w1[(384 + k) * 80 + o];
    }
    for (int idx = tid; idx < 80 * 40; idx += 256) w2s[idx] = w2[idx];
    if (tid < 80) {
        float a = b1[tid];
#pragma unroll 4
        for (int k = 0; k < DD; ++k) a += qps[k] * (w1[k * 80 + tid] + w1[(256 + k) * 80 + tid]);
        qc[tid] = a;
    }
    __syncthreads();

    for (int t0 = 0; t0 < sl; t0 += TCH) {
        for (int idx = tid; idx < TCH * DD; idx += 256) {
            int tl = idx >> 7, c = idx & 127;
            int tt = t0 + tl;
            xs[tl][c] = (tt < sl) ? __bfloat162float(rnn1[((size_t)b * TT_ + tt) * DD + c]) : 0.f;
        }
        __syncthreads();
        for (int u = tid; u < TCH * 80; u += 256) {
            int tl = u / 80, o = u - 80 * tl;
            float s = qc[o];
#pragma unroll 4
            for (int k = 0; k < DD; ++k) s += xs[tl][k] * Weff[k][o];
            a1s[tl][o] = sigmoidf_(s);
        }
        __syncthreads();
        for (int u = tid; u < TCH * 40; u += 256) {
            int tl = u / 40, o = u - 40 * tl;
            float s = b2s[o];
#pragma unroll 4
            for (int k = 0; k < 80; ++k) s += a1s[tl][k] * w2s[k * 40 + o];
            a2s[tl][o] = sigmoidf_(s);
        }
        __syncthreads();
        if (tid < TCH) {
            float s = b3[0];
#pragma unroll 4
            for (int k = 0; k < 40; ++k) s += a2s[tid][k] * w3s[k];
            int tt = t0 + tid;
            if (tt < sl) scores[tt] = s;
        }
        __syncthreads();
    }

    // masked softmax over valid t (invalid terms are exactly 0 in the reference)
    float m = -1e30f;
    for (int i = tid; i < sl; i += 256) m = fmaxf(m, scores[i]);
    for (int o = 32; o > 0; o >>= 1) m = fmaxf(m, __shfl_xor(m, o, 64));
    if ((tid & 63) == 0) red[tid >> 6] = m;
    __syncthreads();
    m = fmaxf(fmaxf(red[0], red[1]), fmaxf(red[2], red[3]));
    float ssum = 0.f;
    for (int i = tid; i < sl; i += 256) {
        float e = __expf(scores[i] - m);
        scores[i] = e;
        ssum += e;
    }
    for (int o = 32; o > 0; o >>= 1) ssum += __shfl_xor(ssum, o, 64);
    if ((tid & 63) == 0) red[4 + (tid >> 6)] = ssum;
    __syncthreads();
    ssum = red[4] + red[5] + red[6] + red[7];
    float inv = 1.f / ssum;
    for (int i = tid; i < sl; i += 256) alphas[(size_t)b * TT_ + i] = scores[i] * inv;
}

// ---------------- out[:, 0:384] = [q | sum | q*sum] ----------------
__global__ __launch_bounds__(256) void k_out(const float* __restrict__ item_eb, const float* __restrict__ ihs,
                                             float* __restrict__ out) {
    int idx = blockIdx.x * 256 + threadIdx.x;
    if (idx >= BB * DD) return;
    int b = idx >> 7, j = idx & 127;
    float q = item_eb[idx];
    float s = ihs[idx];
    size_t base = (size_t)b * (4 * HH);
    out[base + j] = q;
    out[base + HH + j] = s;
    out[base + 2 * HH + j] = q * s;
}

extern "C" void kernel_launch(void* const* d_in, const int* in_sizes, int n_in,
                              void* d_out, int out_size, void* d_ws, size_t ws_size,
                              hipStream_t stream) {
    const float* item_eb = (const float*)d_in[0];
    const float* item_his = (const float*)d_in[1];
    const float* ihs = (const float*)d_in[2];
    const int* mask = (const int*)d_in[3];
    const float* gk1 = (const float*)d_in[4];
    const float* gb1 = (const float*)d_in[5];
    const float* ck1 = (const float*)d_in[6];
    const float* cb1 = (const float*)d_in[7];
    const float* wq = (const float*)d_in[8];
    const float* bq = (const float*)d_in[9];
    const float* pra = (const float*)d_in[10];
    const float* w1 = (const float*)d_in[11];
    const float* b1 = (const float*)d_in[12];
    const float* w2 = (const float*)d_in[13];
    const float* b2 = (const float*)d_in[14];
    const float* w3 = (const float*)d_in[15];
    const float* b3 = (const float*)d_in[16];
    const float* gk2 = (const float*)d_in[17];
    const float* gb2 = (const float*)d_in[18];
    const float* ck2 = (const float*)d_in[19];
    const float* cb2 = (const float*)d_in[20];

    char* ws = (char*)d_ws;
    int* sl = (int*)ws;
    int* perm = (int*)(ws + 8192);
    float* qp = (float*)(ws + 16384);
    float* alphas = (float*)(ws + 16384 + (size_t)BB * HH * 4);
    __hip_bfloat16* rnn1 = (__hip_bfloat16*)(ws + 16384 + (size_t)BB * HH * 4 + (size_t)BB * TT_ * 4);

    float* out = (float*)d_out;

    k_seqlen<<<(BB + 255) / 256, 256, 0, stream>>>(mask, sl);
    k_sort<<<1, 256, 0, stream>>>(sl, perm);
    k_qp<<<BB, 128, 0, stream>>>(item_eb, wq, bq, pra, qp);
    k_gru<false><<<BB / 8, 256, 0, stream>>>(item_his, nullptr, gk1, gb1, ck1, cb1, nullptr, perm, sl, rnn1, nullptr);
    k_mlp<<<BB, 256, 0, stream>>>(rnn1, qp, w1, b1, w2, b2, w3, b3, sl, alphas);
    k_gru<true><<<BB / 8, 256, 0, stream>>>(nullptr, rnn1, gk2, gb2, ck2, cb2, alphas, perm, sl, nullptr, out);
    k_out<<<(BB * DD + 255) / 256, 256, 0, stream>>>(item_eb, ihs, out);
}

// Round 3
// 1807.200 us; speedup vs baseline: 5.9055x; 5.9055x over previous
//
#include <hip/hip_runtime.h>
#include <hip/hip_bf16.h>

// DIEN: seq_len -> sort -> qp(prelu) -> prep(weights->MFMA frags) -> GRU1(MFMA) -> MLP+softmax -> GRU2(MFMA) -> out
// B=2048, T=200, D=128, H=128.
// ws: sl[8KB] | perm[8KB] | qp[1MB] | alphas[1.6MB] | rnn1 bf16[105MB] | wz1|wc1|wz2|wc2 frags [384KB]

#define BB 2048
#define TT_ 200
#define DD 128
#define HH 128

typedef __bf16 bf16x8 __attribute__((ext_vector_type(8)));
typedef float f32x4 __attribute__((ext_vector_type(4)));

__device__ __forceinline__ float sigmoidf_(float x) { return 1.0f / (1.0f + __expf(-x)); }
__device__ __forceinline__ float tanhf_(float x) {
    float s = __expf(-2.f * x);
    return 1.f - 2.f * s / (1.f + s);
}

// ---------------- seq_len ----------------
__global__ __launch_bounds__(256) void k_seqlen(const int* __restrict__ mask, int* __restrict__ sl) {
    int b = blockIdx.x * 256 + threadIdx.x;
    if (b >= BB) return;
    const int* mrow = mask + (size_t)b * TT_;
    int s = TT_;
    for (int t = 0; t < TT_; ++t) {
        if (mrow[t] == 0) { s = t; break; }
    }
    sl[b] = s;
}

// ---------------- counting sort by seq_len ----------------
__global__ __launch_bounds__(256) void k_sort(const int* __restrict__ sl, int* __restrict__ perm) {
    __shared__ int offs[TT_ + 1];
    int tid = threadIdx.x;
    for (int i = tid; i <= TT_; i += 256) offs[i] = 0;
    __syncthreads();
    for (int b = tid; b < BB; b += 256) atomicAdd(&offs[sl[b]], 1);
    __syncthreads();
    if (tid == 0) {
        int acc = 0;
        for (int v = 0; v <= TT_; ++v) { int c = offs[v]; offs[v] = acc; acc += c; }
    }
    __syncthreads();
    for (int b = tid; b < BB; b += 256) {
        int p = atomicAdd(&offs[sl[b]], 1);
        perm[p] = b;
    }
}

// ---------------- qp = prelu(q @ wq + bq) ----------------
__global__ __launch_bounds__(128) void k_qp(const float* __restrict__ item_eb, const float* __restrict__ wq,
                                            const float* __restrict__ bq, const float* __restrict__ alpha,
                                            float* __restrict__ qp) {
    int b = blockIdx.x, j = threadIdx.x;
    __shared__ float qs[DD];
    qs[j] = item_eb[(size_t)b * DD + j];
    __syncthreads();
    float acc = bq[j];
#pragma unroll 4
    for (int k = 0; k < DD; ++k) acc += qs[k] * wq[k * HH + j];
    float v = acc > 0.f ? acc : alpha[j] * acc;
    qp[(size_t)b * HH + j] = v;
}

// ---------------- weight -> MFMA B-fragment prep ----------------
// frag value for tile (nt,kt), lane l, elem e = W[kt*32 + (l>>4)*8 + e][nt*16 + (l&15)]
// stored at dst[tile*512 + lane*8 + e] (bf16), tile = nt*8 + kt
__global__ __launch_bounds__(64) void k_prep(const float* __restrict__ gk1, const float* __restrict__ ck1,
                                             const float* __restrict__ gk2, const float* __restrict__ ck2,
                                             __bf16* __restrict__ wz1, __bf16* __restrict__ wc1,
                                             __bf16* __restrict__ wz2, __bf16* __restrict__ wc2) {
    int tile = blockIdx.x, lane = threadIdx.x;
    const float* W;
    __bf16* dst;
    int N, t2;
    if (tile < 128)      { W = gk1; dst = wz1; N = 256; t2 = tile; }
    else if (tile < 192) { W = ck1; dst = wc1; N = 128; t2 = tile - 128; }
    else if (tile < 320) { W = gk2; dst = wz2; N = 256; t2 = tile - 192; }
    else                 { W = ck2; dst = wc2; N = 128; t2 = tile - 320; }
    int nt = t2 >> 3, kt = t2 & 7;
    int col = nt * 16 + (lane & 15);
    int k0 = kt * 32 + (lane >> 4) * 8;
    bf16x8 v;
#pragma unroll
    for (int e = 0; e < 8; ++e) v[e] = (__bf16)W[(k0 + e) * N + col];
    *(bf16x8*)(dst + (size_t)t2 * 512 + lane * 8) = v;
}

// ---------------- MFMA GRU ----------------
// 256 threads = 4 waves, 8 batch rows (M=16 MFMA, rows 8..15 wasted).
// Wave w: z n-tiles {w,w+4,w+8,w+12}, c n-tiles {w,w+4}. B-frags in VGPRs.
// LDS A layout: xh[kt][hi*128 + row*8 + e] (lane-linear read at [kt][lane*8]).
template <bool IS_GRU2>
__global__ __launch_bounds__(256, 1) void k_gru_mfma(const float* __restrict__ xf,
                                                     const __hip_bfloat16* __restrict__ xbf,
                                                     const __bf16* __restrict__ wz, const __bf16* __restrict__ wc,
                                                     const float* __restrict__ gb, const float* __restrict__ cb,
                                                     const float* __restrict__ alphas,
                                                     const int* __restrict__ perm, const int* __restrict__ slv,
                                                     __hip_bfloat16* __restrict__ rnn1_out,
                                                     float* __restrict__ out) {
    __shared__ __align__(16) __bf16 xh[8][512];   // [x(k0..127) | h(k128..255)]
    __shared__ __align__(16) __bf16 rhs[4][512];  // r*h (k-local 0..127)
    __shared__ int rid_s[8], sl_s[8];
    __shared__ float av_s[8];
    int tid = threadIdx.x;
    int lane = tid & 63, w = tid >> 6;
    int c16 = lane & 15;
    int rb = (lane >> 4) * 4;         // D row base for this lane
    bool rowok = rb < 8;              // rows 8..15 are the wasted M half

    if (tid < 8) {
        int rr = perm[blockIdx.x * 8 + tid];
        rid_s[tid] = rr;
        sl_s[tid] = slv[rr];
    }
    __syncthreads();
    int tmax = 0;
#pragma unroll
    for (int r = 0; r < 8; ++r) tmax = max(tmax, sl_s[r]);
    int slr[4], ridr[4];
#pragma unroll
    for (int i = 0; i < 4; ++i) {
        int rr = rowok ? (rb + i) : 0;
        slr[i] = rowok ? sl_s[rr] : -1;
        ridr[i] = rid_s[rr];
    }

    // B fragments -> registers (stay resident for the whole sequence)
    bf16x8 bz[4][8], bc[2][8];
#pragma unroll
    for (int j = 0; j < 4; ++j)
#pragma unroll
        for (int kt = 0; kt < 8; ++kt)
            bz[j][kt] = *(const bf16x8*)(wz + ((size_t)((w + 4 * j) * 8 + kt)) * 512 + lane * 8);
#pragma unroll
    for (int j = 0; j < 2; ++j)
#pragma unroll
        for (int kt = 0; kt < 8; ++kt)
            bc[j][kt] = *(const bf16x8*)(wc + ((size_t)((w + 4 * j) * 8 + kt)) * 512 + lane * 8);
    float gbv[4], cbv[2];
#pragma unroll
    for (int j = 0; j < 4; ++j) gbv[j] = gb[(w + 4 * j) * 16 + c16];
#pragma unroll
    for (int j = 0; j < 2; ++j) cbv[j] = cb[(w + 4 * j) * 16 + c16];

    float hreg[2][4];
#pragma unroll
    for (int j = 0; j < 2; ++j)
#pragma unroll
        for (int i = 0; i < 4; ++i) hreg[j][i] = 0.f;

    // zero the h region of LDS (rows 0..7)
    int myrow = 0, mych = 0, myrid = 0;
    if (tid < 128) {
        myrow = tid >> 4;
        mych = tid & 15;
        myrid = rid_s[myrow];
        int kt = 4 + (mych >> 2), hi = mych & 3;
        bf16x8 z8;
#pragma unroll
        for (int e = 0; e < 8; ++e) z8[e] = (__bf16)0.f;
        *(bf16x8*)&xh[kt][hi * 128 + myrow * 8] = z8;
    }

    // prefetch t=0
    float4 pa, pb;
    bf16x8 pbf;
    float pav = 0.f;
    if (tid < 128) {
        size_t ga = ((size_t)myrid * TT_ + 0) * HH + mych * 8;
        if constexpr (IS_GRU2) {
            pbf = *(const bf16x8*)((const __bf16*)xbf + ga);
        } else {
            const float4* gp = (const float4*)(xf + ga);
            pa = gp[0];
            pb = gp[1];
        }
    }
    if constexpr (IS_GRU2) {
        if (tid < 8) pav = alphas[(size_t)rid_s[tid] * TT_ + 0];
    }
    __syncthreads();

    for (int t = 0; t < tmax; ++t) {
        // ---- stage x_t (+av), issue prefetch t+1 ----
        if (tid < 128) {
            int kt = mych >> 2, hi = mych & 3;
            bf16x8 v;
            if constexpr (IS_GRU2) {
                v = pbf;
            } else {
#pragma unroll
                for (int e = 0; e < 4; ++e) v[e] = (__bf16)(((const float*)&pa)[e]);
#pragma unroll
                for (int e = 0; e < 4; ++e) v[4 + e] = (__bf16)(((const float*)&pb)[e]);
            }
            *(bf16x8*)&xh[kt][hi * 128 + myrow * 8] = v;
            int tn = min(t + 1, tmax - 1);
            size_t ga = ((size_t)myrid * TT_ + tn) * HH + mych * 8;
            if constexpr (IS_GRU2) {
                pbf = *(const bf16x8*)((const __bf16*)xbf + ga);
            } else {
                const float4* gp = (const float4*)(xf + ga);
                pa = gp[0];
                pb = gp[1];
            }
        }
        if constexpr (IS_GRU2) {
            if (tid < 8) {
                av_s[tid] = pav;
                pav = alphas[(size_t)rid_s[tid] * TT_ + min(t + 1, tmax - 1)];
            }
        }
        __syncthreads();

        // ---- z GEMM: [x|h] @ gk ----
        f32x4 zacc[4];
#pragma unroll
        for (int j = 0; j < 4; ++j) zacc[j] = (f32x4){0.f, 0.f, 0.f, 0.f};
#pragma unroll
        for (int kt = 0; kt < 8; ++kt) {
            bf16x8 a = *(const bf16x8*)&xh[kt][lane * 8];
#pragma unroll
            for (int j = 0; j < 4; ++j)
                zacc[j] = __builtin_amdgcn_mfma_f32_16x16x32_bf16(a, bz[j][kt], zacc[j], 0, 0, 0);
        }
        // ---- z epilogue: sigmoid; r*h -> LDS; u -> regs ----
        float ur[2][4];
#pragma unroll
        for (int j = 0; j < 4; ++j) {
#pragma unroll
            for (int i = 0; i < 4; ++i) {
                float zv = sigmoidf_(zacc[j][i] + gbv[j]);
                if (j < 2) {
                    if (rowok) {
                        float rh = zv * hreg[j][i];
                        int colg = (w + 4 * j) * 16 + c16;  // 0..127
                        int row = rb + i;
                        int kt2 = colg >> 5, hi2 = (colg >> 3) & 3, e2 = colg & 7;
                        rhs[kt2][hi2 * 128 + row * 8 + e2] = (__bf16)rh;
                    }
                } else {
                    ur[j - 2][i] = zv;
                }
            }
        }
        __syncthreads();

        // ---- c GEMM: [x|r*h] @ ck ----
        f32x4 cacc[2];
#pragma unroll
        for (int j = 0; j < 2; ++j) cacc[j] = (f32x4){0.f, 0.f, 0.f, 0.f};
#pragma unroll
        for (int kt = 0; kt < 4; ++kt) {
            bf16x8 a = *(const bf16x8*)&xh[kt][lane * 8];
#pragma unroll
            for (int j = 0; j < 2; ++j)
                cacc[j] = __builtin_amdgcn_mfma_f32_16x16x32_bf16(a, bc[j][kt], cacc[j], 0, 0, 0);
        }
#pragma unroll
        for (int kt = 0; kt < 4; ++kt) {
            bf16x8 a = *(const bf16x8*)&rhs[kt][lane * 8];
#pragma unroll
            for (int j = 0; j < 2; ++j)
                cacc[j] = __builtin_amdgcn_mfma_f32_16x16x32_bf16(a, bc[j][kt + 4], cacc[j], 0, 0, 0);
        }
        // ---- c epilogue: tanh, h update, write h (LDS + rnn1/out) ----
        float avv[4];
        if constexpr (IS_GRU2) {
#pragma unroll
            for (int i = 0; i < 4; ++i) avv[i] = rowok ? av_s[rb + i] : 0.f;
        }
#pragma unroll
        for (int j = 0; j < 2; ++j) {
#pragma unroll
            for (int i = 0; i < 4; ++i) {
                float cv = tanhf_(cacc[j][i] + cbv[j]);
                float u = ur[j][i];
                if constexpr (IS_GRU2) u *= (1.f - avv[i]);
                float nh = u * hreg[j][i] + (1.f - u) * cv;
                bool wr = rowok && (t < slr[i]);
                if (wr) {
                    hreg[j][i] = nh;
                    int colg = (w + 4 * j) * 16 + c16;
                    int row = rb + i;
                    int kk = 128 + colg;
                    int kt2 = kk >> 5, hi2 = (kk >> 3) & 3, e2 = kk & 7;
                    xh[kt2][hi2 * 128 + row * 8 + e2] = (__bf16)nh;
                    if constexpr (!IS_GRU2)
                        rnn1_out[((size_t)ridr[i] * TT_ + t) * HH + colg] = __float2bfloat16(nh);
                }
            }
        }
        __syncthreads();
    }

    if constexpr (IS_GRU2) {
        if (rowok) {
#pragma unroll
            for (int j = 0; j < 2; ++j)
#pragma unroll
                for (int i = 0; i < 4; ++i)
                    out[(size_t)ridr[i] * (4 * HH) + 3 * HH + (w + 4 * j) * 16 + c16] = hreg[j][i];
        }
    }
}

// ---------------- attention MLP + masked softmax (unchanged) ----------------
#define TCH 12
__global__ __launch_bounds__(256) void k_mlp(const __hip_bfloat16* __restrict__ rnn1, const float* __restrict__ qp,
                                             const float* __restrict__ w1, const float* __restrict__ b1,
                                             const float* __restrict__ w2, const float* __restrict__ b2,
                                             const float* __restrict__ w3, const float* __restrict__ b3,
                                             const int* __restrict__ slv, float* __restrict__ alphas) {
    __shared__ float Weff[DD][80];
    __shared__ float qc[80];
    __shared__ float w2s[80 * 40];
    __shared__ float w3s[40], b2s[40];
    __shared__ float qps[DD];
    __shared__ float xs[TCH][DD];
    __shared__ float a1s[TCH][80];
    __shared__ float a2s[TCH][40];
    __shared__ float scores[TT_];
    __shared__ float red[8];
    int b = blockIdx.x, tid = threadIdx.x;
    int sl = slv[b];
    if (tid < DD) qps[tid] = qp[(size_t)b * DD + tid];
    if (tid < 40) { w3s[tid] = w3[tid]; b2s[tid] = b2[tid]; }
    __syncthreads();
    for (int idx = tid; idx < DD * 80; idx += 256) {
        int k = idx / 80, o = idx - 80 * k;
        Weff[k][o] = w1[(128 + k) * 80 + o] - w1[(256 + k) * 80 + o] + qps[k] * w1[(384 + k) * 80 + o];
    }
    for (int idx = tid; idx < 80 * 40; idx += 256) w2s[idx] = w2[idx];
    if (tid < 80) {
        float a = b1[tid];
#pragma unroll 4
        for (int k = 0; k < DD; ++k) a += qps[k] * (w1[k * 80 + tid] + w1[(256 + k) * 80 + tid]);
        qc[tid] = a;
    }
    __syncthreads();

    for (int t0 = 0; t0 < sl; t0 += TCH) {
        for (int idx = tid; idx < TCH * DD; idx += 256) {
            int tl = idx >> 7, c = idx & 127;
            int tt = t0 + tl;
            xs[tl][c] = (tt < sl) ? __bfloat162float(rnn1[((size_t)b * TT_ + tt) * DD + c]) : 0.f;
        }
        __syncthreads();
        for (int u = tid; u < TCH * 80; u += 256) {
            int tl = u / 80, o = u - 80 * tl;
            float s = qc[o];
#pragma unroll 4
            for (int k = 0; k < DD; ++k) s += xs[tl][k] * Weff[k][o];
            a1s[tl][o] = sigmoidf_(s);
        }
        __syncthreads();
        for (int u = tid; u < TCH * 40; u += 256) {
            int tl = u / 40, o = u - 40 * tl;
            float s = b2s[o];
#pragma unroll 4
            for (int k = 0; k < 80; ++k) s += a1s[tl][k] * w2s[k * 40 + o];
            a2s[tl][o] = sigmoidf_(s);
        }
        __syncthreads();
        if (tid < TCH) {
            float s = b3[0];
#pragma unroll 4
            for (int k = 0; k < 40; ++k) s += a2s[tid][k] * w3s[k];
            int tt = t0 + tid;
            if (tt < sl) scores[tt] = s;
        }
        __syncthreads();
    }

    float m = -1e30f;
    for (int i = tid; i < sl; i += 256) m = fmaxf(m, scores[i]);
    for (int o = 32; o > 0; o >>= 1) m = fmaxf(m, __shfl_xor(m, o, 64));
    if ((tid & 63) == 0) red[tid >> 6] = m;
    __syncthreads();
    m = fmaxf(fmaxf(red[0], red[1]), fmaxf(red[2], red[3]));
    float ssum = 0.f;
    for (int i = tid; i < sl; i += 256) {
        float e = __expf(scores[i] - m);
        scores[i] = e;
        ssum += e;
    }
    for (int o = 32; o > 0; o >>= 1) ssum += __shfl_xor(ssum, o, 64);
    if ((tid & 63) == 0) red[4 + (tid >> 6)] = ssum;
    __syncthreads();
    ssum = red[4] + red[5] + red[6] + red[7];
    float inv = 1.f / ssum;
    for (int i = tid; i < sl; i += 256) alphas[(size_t)b * TT_ + i] = scores[i] * inv;
}

// ---------------- out[:, 0:384] = [q | sum | q*sum] ----------------
__global__ __launch_bounds__(256) void k_out(const float* __restrict__ item_eb, const float* __restrict__ ihs,
                                             float* __restrict__ out) {
    int idx = blockIdx.x * 256 + threadIdx.x;
    if (idx >= BB * DD) return;
    int b = idx >> 7, j = idx & 127;
    float q = item_eb[idx];
    float s = ihs[idx];
    size_t base = (size_t)b * (4 * HH);
    out[base + j] = q;
    out[base + HH + j] = s;
    out[base + 2 * HH + j] = q * s;
}

extern "C" void kernel_launch(void* const* d_in, const int* in_sizes, int n_in,
                              void* d_out, int out_size, void* d_ws, size_t ws_size,
                              hipStream_t stream) {
    const float* item_eb = (const float*)d_in[0];
    const float* item_his = (const float*)d_in[1];
    const float* ihs = (const float*)d_in[2];
    const int* mask = (const int*)d_in[3];
    const float* gk1 = (const float*)d_in[4];
    const float* gb1 = (const float*)d_in[5];
    const float* ck1 = (const float*)d_in[6];
    const float* cb1 = (const float*)d_in[7];
    const float* wq = (const float*)d_in[8];
    const float* bq = (const float*)d_in[9];
    const float* pra = (const float*)d_in[10];
    const float* w1 = (const float*)d_in[11];
    const float* b1 = (const float*)d_in[12];
    const float* w2 = (const float*)d_in[13];
    const float* b2 = (const float*)d_in[14];
    const float* w3 = (const float*)d_in[15];
    const float* b3 = (const float*)d_in[16];
    const float* gk2 = (const float*)d_in[17];
    const float* gb2 = (const float*)d_in[18];
    const float* ck2 = (const float*)d_in[19];
    const float* cb2 = (const float*)d_in[20];

    char* ws = (char*)d_ws;
    int* sl = (int*)ws;
    int* perm = (int*)(ws + 8192);
    float* qp = (float*)(ws + 16384);
    float* alphas = (float*)(ws + 16384 + (size_t)BB * HH * 4);
    __hip_bfloat16* rnn1 = (__hip_bfloat16*)(ws + 16384 + (size_t)BB * HH * 4 + (size_t)BB * TT_ * 4);
    size_t WOFF = 16384 + (size_t)BB * HH * 4 + (size_t)BB * TT_ * 4 + (size_t)BB * TT_ * HH * 2;
    __bf16* wz1 = (__bf16*)(ws + WOFF);
    __bf16* wc1 = (__bf16*)(ws + WOFF + 131072);
    __bf16* wz2 = (__bf16*)(ws + WOFF + 196608);
    __bf16* wc2 = (__bf16*)(ws + WOFF + 327680);

    float* out = (float*)d_out;

    k_seqlen<<<(BB + 255) / 256, 256, 0, stream>>>(mask, sl);
    k_sort<<<1, 256, 0, stream>>>(sl, perm);
    k_qp<<<BB, 128, 0, stream>>>(item_eb, wq, bq, pra, qp);
    k_prep<<<384, 64, 0, stream>>>(gk1, ck1, gk2, ck2, wz1, wc1, wz2, wc2);
    k_gru_mfma<false><<<BB / 8, 256, 0, stream>>>(item_his, nullptr, wz1, wc1, gb1, cb1, nullptr, perm, sl, rnn1, nullptr);
    k_mlp<<<BB, 256, 0, stream>>>(rnn1, qp, w1, b1, w2, b2, w3, b3, sl, alphas);
    k_gru_mfma<true><<<BB / 8, 256, 0, stream>>>(nullptr, rnn1, wz2, wc2, gb2, cb2, alphas, perm, sl, nullptr, out);
    k_out<<<(BB * DD + 255) / 256, 256, 0, stream>>>(item_eb, ihs, out);
}